// Round 2
// baseline (223.611 us; speedup 1.0000x reference)
//
#include <hip/hip_runtime.h>

// Reference: out = x @ eye(4096) == x. Pure float32 copy, memory-bound.
// 8192*4096 floats = 134.2 MB; 268 MB total traffic; floor ≈ 43 µs @ 6.3 TB/s.
//
// Round-1 evidence: rocprof top-5 shows only harness poison fills (81 µs,
// 6.6 TB/s); our copy dispatch was < 81 µs. The 221 µs timed number includes
// ~140+ µs of per-iteration harness re-poison/restore traffic we don't control.
// This round: delegate the copy to the driver's optimized d2d blit path
// (hipMemcpyAsync is explicitly allowed under graph capture).

extern "C" void kernel_launch(void* const* d_in, const int* in_sizes, int n_in,
                              void* d_out, int out_size, void* d_ws, size_t ws_size,
                              hipStream_t stream) {
    const void* x = d_in[0];
    size_t bytes = (size_t)out_size * sizeof(float);  // 134,217,728 bytes
    hipMemcpyAsync(d_out, x, bytes, hipMemcpyDeviceToDevice, stream);
}